// Round 7
// baseline (282.048 us; speedup 1.0000x reference)
//
#include <hip/hip_runtime.h>
#include <stdint.h>

#define NCLS 172
#define IGN 255
#define HW 65536          // 256*256
#define NPIX 262144       // 4*256*256
#define EPSV 1e-7f
#define TP 128            // pixels per block: 512B contiguous per class row
#define NTHR 512          // 8 waves
#define HCLS 86           // classes per half-stage
#define HROWS 96          // padded rows (48 DMA instr x 2 rows)
#define HSZ (HROWS * TP)  // 12288 floats = 49152 B
#define NSTAGE 32
#define SS 520            // [0,172) inter | [172,344) cnt | [344,516) union | 516 ce | 517 nvalid

__device__ __forceinline__ void gl_lds16(const float* g, float* l) {
    __builtin_amdgcn_global_load_lds(
        (const __attribute__((address_space(1))) void*)g,
        (__attribute__((address_space(3))) void*)l, 16, 0, 0);
}

// Conservative 512B-row variant: 512 threads, 54KB LDS, no inline asm.
// Per block (128 pixels): stage half0 (86 rows x 512B, 48 dwordx4 DMA) ->
// sync -> exp into e[] regs -> sync -> stage half1 into SAME buffer -> sync ->
// exp rest + per-pixel sum -> finalize (invs, owner-CE, union butterfly).
// Class ownership: thread (p=tid&127, chunk=tid>>7) owns c = chunk + 4k.
__global__ __launch_bounds__(NTHR, 4) void seg_fused(
    const float* __restrict__ pred, const int* __restrict__ tgt,
    float* __restrict__ part)
{
    __shared__ float tile[HSZ];        // 49152 B, linear (DMA dest), reused per half
    __shared__ float sPart[4 * TP];    // per-chunk per-pixel partial sums
    __shared__ int   sTgt[TP];
    __shared__ float sInter[NCLS];
    __shared__ float sUnion[NCLS];
    __shared__ unsigned int sCnt[NCLS];
    __shared__ float sCE[2];           // [0]=ce sum, [1]=nvalid

    const int tid   = threadIdx.x;
    const int lane  = tid & 63;
    const int wv    = tid >> 6;        // 0..7
    const int p     = tid & (TP - 1);  // 0..127
    const int chunk = tid >> 7;        // 0..3: classes c = chunk + 4k, k=0..42

    for (int i = tid; i < NCLS; i += NTHR) { sInter[i] = 0.f; sUnion[i] = 0.f; sCnt[i] = 0u; }
    if (tid < 2) sCE[tid] = 0.f;
    const int pix0 = blockIdx.x * TP;
    if (tid < TP) sTgt[tid] = tgt[pix0 + tid];

    const int b   = pix0 >> 16;
    const int hw0 = pix0 & (HW - 1);
    const float* gb = pred + (size_t)b * NCLS * HW + hw0;

    const int srow = lane >> 5;        // row within instr (0..1)
    const int spo  = (lane & 31) << 2; // pixel float offset (0..124)

    auto stage = [&](int half) {       // 6 DMA instrs per wave, 48 total
        const int coff = half * HCLS;
        #pragma unroll
        for (int k6 = 0; k6 < 6; ++k6) {
            const int ib = wv + 8 * k6;            // 0..47
            int c = coff + 2 * ib + srow;          // pad rows clamp to 171
            if (c > NCLS - 1) c = NCLS - 1;
            gl_lds16(gb + (size_t)c * HW + spo, &tile[ib * 256]);
        }
    };

    float e[43];
    float sAcc = 0.f;

    // ---- half 0: classes 0..85 ----
    stage(0);
    __syncthreads();                   // compiler-emitted vmcnt(0) drain
    #pragma unroll
    for (int k = 0; k < 43; ++k) {     // static e-index, runtime guard (rule #20)
        const int c = chunk + 4 * k;
        if (c < HCLS) { e[k] = __expf(tile[c * TP + p]); sAcc += e[k]; }
        else          { e[k] = 0.f; }
    }
    __syncthreads();                   // all reads done before buffer reuse

    // ---- half 1: classes 86..171 into the same buffer ----
    stage(1);
    __syncthreads();
    #pragma unroll
    for (int k = 0; k < 43; ++k) {
        const int c = chunk + 4 * k;
        if (c >= HCLS) { e[k] = __expf(tile[(c - HCLS) * TP + p]); sAcc += e[k]; }
    }
    sPart[chunk * TP + p] = sAcc;
    __syncthreads();

    // ---- finalize: invs + owner-CE + union (no tile access) ----
    const float s = (sPart[p] + sPart[TP + p]) + (sPart[2 * TP + p] + sPart[3 * TP + p]);
    const float invs = 1.0f / s;

    const int t = sTgt[p];
    const bool valid = (t != IGN);
    float nll = 0.f, nv = 0.f;
    if (valid && (t & 3) == chunk) {   // unique owner thread for pixel p
        float pt = 0.f;
        #pragma unroll
        for (int k = 0; k < 43; ++k)   // static extract of e[t>>2]
            if ((t >> 2) == k) pt = e[k];
        pt *= invs;
        nll = -__logf(pt); nv = 1.f;
        atomicAdd(&sInter[t], pt);
        atomicAdd(&sCnt[t], 1u);
    }
    #pragma unroll
    for (int off = 32; off > 0; off >>= 1) {
        nll += __shfl_down(nll, off, 64);
        nv  += __shfl_down(nv,  off, 64);
    }
    if (lane == 0 && nv != 0.f) { atomicAdd(&sCE[0], nll); atomicAdd(&sCE[1], nv); }

    // union: butterfly over the wave's 64 pixels, 2 waves/chunk combine in LDS
    #pragma unroll
    for (int k = 0; k < 43; ++k) {
        float v = e[k] * invs;
        #pragma unroll
        for (int m = 32; m > 0; m >>= 1) v += __shfl_xor(v, m, 64);
        if (lane == 0) atomicAdd(&sUnion[chunk + 4 * k], v);
    }
    __syncthreads();

    // ---- flush per-block partials to staged global buffers ----
    float* pb = part + (size_t)(blockIdx.x & (NSTAGE - 1)) * SS;
    if (tid < NCLS) {
        const float vi = sInter[tid];
        if (vi != 0.f) atomicAdd(&pb[tid], vi);
        const unsigned int ci = sCnt[tid];
        if (ci != 0u) atomicAdd(&pb[NCLS + tid], (float)ci);
        atomicAdd(&pb[344 + tid], sUnion[tid]);
    }
    if (tid == 0) { atomicAdd(&pb[516], sCE[0]); atomicAdd(&pb[517], sCE[1]); }
}

__global__ __launch_bounds__(256) void seg_fin(
    const float* __restrict__ part, float* __restrict__ out)
{
    __shared__ float sT[256], sN[256];
    const int tid = threadIdx.x;
    float term = 0.f, nv = 0.f;
    if (tid < NCLS) {
        float inter = 0.f, cnt = 0.f, uni = 0.f;
        for (int st = 0; st < NSTAGE; ++st) {
            inter += part[st * SS + tid];
            cnt   += part[st * SS + NCLS + tid];
            uni   += part[st * SS + 344 + tid];
        }
        const float u = uni + cnt;
        if (u > 0.f) { term = (2.f * inter + EPSV) / (u + EPSV); nv = 1.f; }
    }
    sT[tid] = term; sN[tid] = nv;
    __syncthreads();
    #pragma unroll
    for (int s2 = 128; s2 > 0; s2 >>= 1) {
        if (tid < s2) { sT[tid] += sT[tid + s2]; sN[tid] += sN[tid + s2]; }
        __syncthreads();
    }
    if (tid == 0) {
        float ce = 0.f, nvl = 0.f;
        for (int st = 0; st < NSTAGE; ++st) {
            ce  += part[st * SS + 516];
            nvl += part[st * SS + 517];
        }
        const float ceo  = ce / fmaxf(nvl, 1.f);
        const float dice = (sN[0] > 0.f) ? (1.f - sT[0] / fmaxf(sN[0], 1.f)) : 0.f;
        out[0] = ceo + 0.5f * dice;
    }
}

extern "C" void kernel_launch(void* const* d_in, const int* in_sizes, int n_in,
                              void* d_out, int out_size, void* d_ws, size_t ws_size,
                              hipStream_t stream) {
    const float* pred = (const float*)d_in[0];
    const int*   tgt  = (const int*)d_in[1];
    float* out  = (float*)d_out;
    float* part = (float*)d_ws;

    hipMemsetAsync(d_ws, 0, NSTAGE * SS * sizeof(float), stream);
    seg_fused<<<NPIX / TP, NTHR, 0, stream>>>(pred, tgt, part);
    seg_fin<<<1, 256, 0, stream>>>(part, out);
}

// Round 8
// 268.452 us; speedup vs baseline: 1.0506x; 1.0506x over previous
//
#include <hip/hip_runtime.h>
#include <stdint.h>

#define NCLS 172
#define IGN 255
#define HW 65536          // 256*256
#define NPIX 262144       // 4*256*256
#define EPSV 1e-7f
#define TP 128            // pixels per block
#define NTHR 512          // 8 waves
#define CPC 43            // classes per chunk (4 chunks x 43 = 172)
#define NSTAGE 32
#define SS 520            // [0,172) inter | [172,344) cnt | [344,516) union | 516 ce | 517 nvalid

// Register-direct fused kernel: NO global_load_lds, NO LDS tile.
// Theory: gfx950's LDS-DMA path serviced ~1 KB per ~105-140ns per CU in every
// prior round (the ~2 TB/s plateau); plain VGPR loads sustain 6.3 TB/s (m13).
// Thread (p=tid&127, chunk=tid>>7) loads its 43 class logits for pixel p
// directly to registers (wave-instr = 256B contiguous, 43-deep MLP), exps in
// place, reduces the per-pixel sum via 3KB of LDS scratch, then does owner-CE
// and a per-class butterfly for the union -- all from registers.
__global__ __launch_bounds__(NTHR) void seg_fused(
    const float* __restrict__ pred, const int* __restrict__ tgt,
    float* __restrict__ part)
{
    __shared__ float sPart[4 * TP];    // per-chunk per-pixel partial sums
    __shared__ float sInter[NCLS];
    __shared__ float sUnion[NCLS];
    __shared__ unsigned int sCnt[NCLS];
    __shared__ float sCE[2];           // [0]=ce sum, [1]=nvalid

    const int tid   = threadIdx.x;
    const int lane  = tid & 63;
    const int p     = tid & (TP - 1);  // 0..127 pixel
    const int chunk = tid >> 7;        // 0..3
    const int c0    = chunk * CPC;

    for (int i = tid; i < NCLS; i += NTHR) { sInter[i] = 0.f; sUnion[i] = 0.f; sCnt[i] = 0u; }
    if (tid < 2) sCE[tid] = 0.f;

    const int pix0 = blockIdx.x * TP;
    const int b    = pix0 >> 16;
    const int hw0  = pix0 & (HW - 1);
    const float* gp = pred + (size_t)b * NCLS * HW + (size_t)c0 * HW + hw0 + p;

    // ---- load 43 classes straight to VGPRs, exp in place, 4-way sum ILP ----
    float e[CPC];
    float s0 = 0.f, s1 = 0.f, s2 = 0.f, s3 = 0.f;
    #pragma unroll
    for (int k = 0; k < 40; k += 4) {
        e[k]     = __expf(gp[(size_t)(k    ) * HW]);
        e[k + 1] = __expf(gp[(size_t)(k + 1) * HW]);
        e[k + 2] = __expf(gp[(size_t)(k + 2) * HW]);
        e[k + 3] = __expf(gp[(size_t)(k + 3) * HW]);
        s0 += e[k]; s1 += e[k + 1]; s2 += e[k + 2]; s3 += e[k + 3];
    }
    e[40] = __expf(gp[(size_t)40 * HW]); s0 += e[40];
    e[41] = __expf(gp[(size_t)41 * HW]); s1 += e[41];
    e[42] = __expf(gp[(size_t)42 * HW]); s2 += e[42];
    sPart[chunk * TP + p] = (s0 + s1) + (s2 + s3);
    __syncthreads();

    // ---- per-pixel total and invs (every thread computes its pixel's) ----
    const float s = (sPart[p] + sPart[TP + p]) + (sPart[2 * TP + p] + sPart[3 * TP + p]);
    const float invs = 1.0f / s;

    // ---- owner-thread CE: the thread holding e[t%43] in chunk t/43 emits ----
    const int t = tgt[pix0 + p];
    const bool valid = (t != IGN);
    float nll = 0.f, nv = 0.f;
    if (valid && (t / CPC) == chunk) {
        const int kt = t - chunk * CPC;
        float et = 0.f;
        #pragma unroll
        for (int k = 0; k < CPC; ++k)   // static extract (rule #20)
            if (kt == k) et = e[k];
        const float pt = et * invs;
        nll = -__logf(pt); nv = 1.f;
        atomicAdd(&sInter[t], pt);
        atomicAdd(&sCnt[t], 1u);
    }
    #pragma unroll
    for (int off = 32; off > 0; off >>= 1) {
        nll += __shfl_down(nll, off, 64);
        nv  += __shfl_down(nv,  off, 64);
    }
    if (lane == 0 && nv != 0.f) { atomicAdd(&sCE[0], nll); atomicAdd(&sCE[1], nv); }

    // ---- union: butterfly e[k]*invs over the wave's 64 pixels ----
    #pragma unroll
    for (int k = 0; k < CPC; ++k) {
        float v = e[k] * invs;
        #pragma unroll
        for (int m = 32; m > 0; m >>= 1) v += __shfl_xor(v, m, 64);
        if (lane == 0) atomicAdd(&sUnion[c0 + k], v);   // 2 waves per chunk combine
    }
    __syncthreads();

    // ---- flush per-block partials to staged global buffers ----
    float* pb = part + (size_t)(blockIdx.x & (NSTAGE - 1)) * SS;
    if (tid < NCLS) {
        const float vi = sInter[tid];
        if (vi != 0.f) atomicAdd(&pb[tid], vi);
        const unsigned int ci = sCnt[tid];
        if (ci != 0u) atomicAdd(&pb[NCLS + tid], (float)ci);
        atomicAdd(&pb[344 + tid], sUnion[tid]);
    }
    if (tid == 0) { atomicAdd(&pb[516], sCE[0]); atomicAdd(&pb[517], sCE[1]); }
}

__global__ __launch_bounds__(256) void seg_fin(
    const float* __restrict__ part, float* __restrict__ out)
{
    __shared__ float sT[256], sN[256];
    const int tid = threadIdx.x;
    float term = 0.f, nv = 0.f;
    if (tid < NCLS) {
        float inter = 0.f, cnt = 0.f, uni = 0.f;
        for (int st = 0; st < NSTAGE; ++st) {
            inter += part[st * SS + tid];
            cnt   += part[st * SS + NCLS + tid];
            uni   += part[st * SS + 344 + tid];
        }
        const float u = uni + cnt;
        if (u > 0.f) { term = (2.f * inter + EPSV) / (u + EPSV); nv = 1.f; }
    }
    sT[tid] = term; sN[tid] = nv;
    __syncthreads();
    #pragma unroll
    for (int s2 = 128; s2 > 0; s2 >>= 1) {
        if (tid < s2) { sT[tid] += sT[tid + s2]; sN[tid] += sN[tid + s2]; }
        __syncthreads();
    }
    if (tid == 0) {
        float ce = 0.f, nvl = 0.f;
        for (int st = 0; st < NSTAGE; ++st) {
            ce  += part[st * SS + 516];
            nvl += part[st * SS + 517];
        }
        const float ceo  = ce / fmaxf(nvl, 1.f);
        const float dice = (sN[0] > 0.f) ? (1.f - sT[0] / fmaxf(sN[0], 1.f)) : 0.f;
        out[0] = ceo + 0.5f * dice;
    }
}

extern "C" void kernel_launch(void* const* d_in, const int* in_sizes, int n_in,
                              void* d_out, int out_size, void* d_ws, size_t ws_size,
                              hipStream_t stream) {
    const float* pred = (const float*)d_in[0];
    const int*   tgt  = (const int*)d_in[1];
    float* out  = (float*)d_out;
    float* part = (float*)d_ws;

    hipMemsetAsync(d_ws, 0, NSTAGE * SS * sizeof(float), stream);
    seg_fused<<<NPIX / TP, NTHR, 0, stream>>>(pred, tgt, part);
    seg_fin<<<1, 256, 0, stream>>>(part, out);
}